// Round 2
// baseline (168.310 us; speedup 1.0000x reference)
//
#include <hip/hip_runtime.h>
#include <hip/hip_bf16.h>

// CausalGraphDiscovery on MI355X. Inputs/outputs are float32 buffers
// (bf16-rounded values; thresholds bf16-scale). Internal compute fp32.
//
// d_out layout (f32): [0,256) adj | [256, 256+131072) predictions | [131328, 131584) scores
//
// ws layout (fp32):
//   [b*272 .. b*272+256)  : per-avg-block partial P1[i][j] = sum_s avg[s,i]avg[s,j]
//   [b*272+256 .. +272)   : per-avg-block partial msum[i]  = sum_s avg[s,i]
//   8704..8944  : scores accumulators (one writer per pair, no atomics)
//   8960..9200  : parent_mask (16x15)
//   9200..9216  : has_parents (16)
//   9400        : dummy (keeps L2-warm loads alive)

#define WS_P1(b)   ((b)*272)
#define WS_SCORES  8704
#define WS_PM      8960
#define WS_HP      9200
#define WS_DUMMY   9400

// ---------------------------------------------------------------- kernel A
__global__ void __launch_bounds__(256) k_avg(
    const float* __restrict__ data,
    const float* __restrict__ Ws1,
    const float* __restrict__ Ws2,
    const float* __restrict__ Ws3,
    float* __restrict__ wsf)
{
    __shared__ float av[16*17];
    int b = blockIdx.x, tid = threadIdx.x;
    int sl = tid >> 4, vv = tid & 15;
    int s = b*16 + sl;
    float acc = 0.f;
    #pragma unroll
    for (int bt = 0; bt < 16; ++bt) acc += data[bt*8192 + s*16 + vv];
    av[sl*17 + vv] = acc * (1.f/16.f);
    __syncthreads();
    int i = tid >> 4, j = tid & 15;
    float p1 = 0.f;
    #pragma unroll
    for (int r = 0; r < 16; ++r) p1 += av[r*17 + i] * av[r*17 + j];
    wsf[WS_P1(b) + tid] = p1;
    if (tid < 16) {
        float ms = 0.f;
        #pragma unroll
        for (int r = 0; r < 16; ++r) ms += av[r*17 + tid];
        wsf[WS_P1(b) + 256 + tid] = ms;
    }
    // Warm every XCD's L2 with the adjacency-MLP weights (the single graph
    // block in the next kernel reads 520 KB alone; cold-HBM would cost ~10us).
    int seg = b >> 3;  // 4 segments, 8 blocks each (covers all XCDs heuristically)
    unsigned xr = 0;
    const uint4* w1 = (const uint4*)Ws1;   // 65536 f32 = 16384 uint4
    for (int e = tid; e < 4096; e += 256) { uint4 u = w1[seg*4096 + e]; xr ^= u.x^u.y^u.z^u.w; }
    const uint4* w2 = (const uint4*)Ws2;   // 32768 f32 = 8192 uint4
    for (int e = tid; e < 2048; e += 256) { uint4 u = w2[seg*2048 + e]; xr ^= u.x^u.y^u.z^u.w; }
    const uint4* w3 = (const uint4*)Ws3;   // 32768 f32 = 8192 uint4
    for (int e = tid; e < 2048; e += 256) { uint4 u = w3[seg*2048 + e]; xr ^= u.x^u.y^u.z^u.w; }
    if (xr == 0x9E3779B9u) wsf[WS_DUMMY] = 0.f;  // never taken in practice; defeats DCE
}

// ---------------------------------------------------------------- kernel B
// block 0: corr -> adjacency MLP -> adj out + parent masks (serial chain)
// blocks 1..240: per-pair score MLP over all 8192 samples (independent work
// overlapping the latency-bound graph block)
__global__ void __launch_bounds__(512) k_graph_pairs(
    const float* __restrict__ data,
    const float* __restrict__ Ws1, const float* __restrict__ bs1,
    const float* __restrict__ Ws2, const float* __restrict__ bs2,
    const float* __restrict__ Ws3, const float* __restrict__ bs3,
    const float* __restrict__ Wt1, const float* __restrict__ bt1,
    const float* __restrict__ Wt2, const float* __restrict__ bt2,
    float* __restrict__ wsf, float* __restrict__ out)
{
    __shared__ float sh[2048];
    int tid = threadIdx.x;

    if (blockIdx.x != 0) {
        // ---- pair block ----
        int p = blockIdx.x - 1;
        int i = p / 15, jr = p % 15;
        int j = jr + (jr >= i ? 1 : 0);
        float* w0 = sh;        // 32
        float* w1 = sh + 32;   // 32
        float* bb = sh + 64;   // 32
        float* w2 = sh + 96;   // 32
        float* red = sh + 128; // 512
        if (tid < 32) {
            w0[tid] = Wt1[p*64 + tid];
            w1[tid] = Wt1[p*64 + 32 + tid];
            bb[tid] = bt1[p*32 + tid];
            w2[tid] = Wt2[p*32 + tid];
        }
        if (tid == 0) sh[700] = bt2[p];
        __syncthreads();
        float b2s = sh[700];
        float acc = 0.f;
        for (int it = 0; it < 16; ++it) {
            int s = it*512 + tid;
            float xa = data[s*16 + i];
            float xb = data[s*16 + j];
            float z = b2s;
            #pragma unroll
            for (int h = 0; h < 32; ++h) {
                float t1 = fmaf(xa, w0[h], fmaf(xb, w1[h], bb[h]));
                z = fmaf(fmaxf(t1, 0.f), w2[h], z);
            }
            acc += 1.f / (1.f + expf(-z));
        }
        red[tid] = acc;
        __syncthreads();
        for (int off = 256; off > 0; off >>= 1) {
            if (tid < off) red[tid] += red[tid + off];
            __syncthreads();
        }
        if (tid == 0) wsf[WS_SCORES + p] = red[0] * (1.f/8192.f);
        return;
    }

    // ---- graph block ----
    float* corr_s = sh;          // 256
    float* part   = sh + 256;    // 512
    float* h1_s   = sh + 768;    // 256
    float* h2_s   = sh + 1024;   // 128
    float* adj_s  = sh + 1152;   // 256
    float* pm_s   = sh + 1408;   // 240
    float* m_s    = sh + 1648;   // 16
    float* std_s  = sh + 1664;   // 16
    float* cov_s  = sh + 1680;   // 256 (ends 1936)

    float p1 = 0.f;
    if (tid < 256) { for (int b = 0; b < 32; ++b) p1 += wsf[WS_P1(b) + tid]; }
    if (tid < 16) {
        float ms = 0.f;
        for (int b = 0; b < 32; ++b) ms += wsf[WS_P1(b) + 256 + tid];
        m_s[tid] = ms * (1.f/512.f);
    }
    __syncthreads();
    if (tid < 256) { int i = tid>>4, j = tid&15; cov_s[tid] = p1 - 512.f*m_s[i]*m_s[j]; }
    __syncthreads();
    if (tid < 16) std_s[tid] = sqrtf(fmaxf(cov_s[tid*17], 0.f));
    __syncthreads();
    if (tid < 256) {
        int i = tid>>4, j = tid&15;
        float den = std_s[i]*std_s[j];
        corr_s[tid] = (den > 0.f && i != j) ? fabsf(cov_s[tid]/den) : 0.f;
    }
    __syncthreads();
    // layer1: 256 outputs, K=256 split in 2 across 512 threads
    {
        int t = tid & 255, half = tid >> 8;
        float a = 0.f;
        #pragma unroll 8
        for (int i = half*128; i < half*128 + 128; ++i)
            a = fmaf(corr_s[i], Ws1[i*256 + t], a);
        part[half*256 + t] = a;
    }
    __syncthreads();
    if (tid < 256) h1_s[tid] = fmaxf(part[tid] + part[256 + tid] + bs1[tid], 0.f);
    __syncthreads();
    // layer2: 128 outputs, K=256 split in 4
    {
        int t = tid & 127, q = tid >> 7;
        float a = 0.f;
        #pragma unroll 8
        for (int i = q*64; i < q*64 + 64; ++i)
            a = fmaf(h1_s[i], Ws2[i*128 + t], a);
        part[q*128 + t] = a;
    }
    __syncthreads();
    if (tid < 128)
        h2_s[tid] = fmaxf(part[tid] + part[128+tid] + part[256+tid] + part[384+tid] + bs2[tid], 0.f);
    __syncthreads();
    // layer3: 256 outputs, K=128 split in 2
    {
        int t = tid & 255, half = tid >> 8;
        float a = 0.f;
        #pragma unroll 8
        for (int i = half*64; i < half*64 + 64; ++i)
            a = fmaf(h2_s[i], Ws3[i*256 + t], a);
        part[half*256 + t] = a;
    }
    __syncthreads();
    if (tid < 256) {
        float z = part[tid] + part[256 + tid] + bs3[tid];
        float a = 1.f / (1.f + expf(-z));
        int r = tid >> 4, c = tid & 15;
        float adjv = (r < c) ? a : 0.f;   // triu(adj, 1)
        adj_s[tid] = adjv;
        out[tid] = adjv;
    }
    __syncthreads();
    if (tid < 240) {
        int v = tid / 15, pr = tid % 15;
        int jj = pr + (pr >= v ? 1 : 0);
        float pmv = (adj_s[jj*16 + v] > 0.5f) ? 1.f : 0.f;
        wsf[WS_PM + tid] = pmv;
        pm_s[tid] = pmv;
    }
    __syncthreads();
    if (tid < 16) {
        float sum = 0.f;
        #pragma unroll
        for (int pr = 0; pr < 15; ++pr) sum += pm_s[tid*15 + pr];
        wsf[WS_HP + tid] = (sum > 0.f) ? 1.f : 0.f;
    }
}

// ---------------------------------------------------------------- kernel C
// blocks 0..511: (var v = bid>>5, 256-sample chunk = bid&31) mech MLP.
// LDS: fp32 weights + 32-sample h1 tile (stride 129 => conflict-free).
// block 512: finalize scores scatter.
#define SM_WM1  0       // 1920
#define SM_BM1  1920    // 128
#define SM_WM2  2048    // 8192
#define SM_BM2  10240   // 64
#define SM_WM3  10304   // 64
#define SM_PM   10368   // 15
#define SM_BM3  10383
#define SM_HP   10384
#define SM_X    10388   // 32*17 = 544
#define SM_H1   10932   // 32*129 = 4128
#define SM_PART 15060   // 256
#define SM_TOT  15320   // 61.3 KB -> 2 blocks/CU

__global__ void __launch_bounds__(256) k_mech_scores(
    const float* __restrict__ data,
    const float* __restrict__ Wm1, const float* __restrict__ bm1,
    const float* __restrict__ Wm2, const float* __restrict__ bm2,
    const float* __restrict__ Wm3, const float* __restrict__ bm3,
    const float* __restrict__ wsf, float* __restrict__ out)
{
    int tid = threadIdx.x, bid = blockIdx.x;
    if (bid == 512) {
        // scores scatter: scores[i][j] = s[i*15 + j - (j>i)], diag = 0
        int i = tid >> 4, j = tid & 15;
        float v = 0.f;
        if (i != j) v = wsf[WS_SCORES + i*15 + j - (j > i ? 1 : 0)];
        out[256 + 131072 + tid] = v;
        return;
    }
    __shared__ float sm[SM_TOT];
    int v = bid >> 5, chunk = bid & 31;
    int gs0 = chunk * 256;

    // stage per-var weights (fp32 LDS), coalesced
    for (int e = tid; e < 1920; e += 256) sm[SM_WM1 + e] = Wm1[v*1920 + e];
    for (int e = tid; e < 128;  e += 256) sm[SM_BM1 + e] = bm1[v*128 + e];
    for (int e = tid; e < 8192; e += 256) sm[SM_WM2 + e] = Wm2[v*8192 + e];
    if (tid < 64)               sm[SM_BM2 + tid]      = bm2[v*64 + tid];
    if (tid >= 64 && tid < 128) sm[SM_WM3 + tid - 64] = Wm3[v*64 + tid - 64];
    if (tid < 15)  sm[SM_PM + tid] = wsf[WS_PM + v*15 + tid];
    if (tid == 15) sm[SM_BM3] = bm3[v];
    if (tid == 16) sm[SM_HP]  = wsf[WS_HP + v];

    const float4* w1v = (const float4*)(sm + SM_WM1);
    const float4* b1v = (const float4*)(sm + SM_BM1);
    const float4* w2v = (const float4*)(sm + SM_WM2);
    const float4* b2v = (const float4*)(sm + SM_BM2);
    const float4* w3v = (const float4*)(sm + SM_WM3);

    for (int sub = 0; sub < 8; ++sub) {         // 8 sub-tiles of 32 samples
        __syncthreads();
        // stage x: 32 samples x 16 vars (pad 17 for bank spread)
        for (int e = tid; e < 512; e += 256) {
            int s = e >> 4, j = e & 15;
            sm[SM_X + s*17 + j] = data[(gs0 + sub*32)*16 + e];
        }
        __syncthreads();
        // pass A: h1[32][128] = relu(inp @ Wm1 + bm1)
        {
            int s = tid & 31, hb = (tid >> 5) * 16;
            float xi[15];
            #pragma unroll
            for (int p = 0; p < 15; ++p) {
                int jj = p + (p >= v ? 1 : 0);
                xi[p] = sm[SM_X + s*17 + jj] * sm[SM_PM + p];
            }
            #pragma unroll
            for (int g = 0; g < 4; ++g) {
                int h = hb + g*4;
                float4 a = b1v[h >> 2];
                #pragma unroll
                for (int p = 0; p < 15; ++p) {
                    float4 w = w1v[(p*128 + h) >> 2];  // wave-uniform -> LDS broadcast
                    a.x = fmaf(xi[p], w.x, a.x);
                    a.y = fmaf(xi[p], w.y, a.y);
                    a.z = fmaf(xi[p], w.z, a.z);
                    a.w = fmaf(xi[p], w.w, a.w);
                }
                sm[SM_H1 + s*129 + h + 0] = fmaxf(a.x, 0.f);
                sm[SM_H1 + s*129 + h + 1] = fmaxf(a.y, 0.f);
                sm[SM_H1 + s*129 + h + 2] = fmaxf(a.z, 0.f);
                sm[SM_H1 + s*129 + h + 3] = fmaxf(a.w, 0.f);
            }
        }
        __syncthreads();
        // pass B: h2 = relu(h1 @ Wm2 + bm2); partial mech = h2 . Wm3
        {
            int s = tid & 31, kb = (tid >> 5) * 8;
            float4 a0 = b2v[kb >> 2], a1 = b2v[(kb >> 2) + 1];
            #pragma unroll 4
            for (int h = 0; h < 128; ++h) {
                float rh = sm[SM_H1 + s*129 + h];
                float4 wA = w2v[(h*64 + kb) >> 2];
                float4 wB = w2v[(h*64 + kb + 4) >> 2];
                a0.x = fmaf(rh, wA.x, a0.x); a0.y = fmaf(rh, wA.y, a0.y);
                a0.z = fmaf(rh, wA.z, a0.z); a0.w = fmaf(rh, wA.w, a0.w);
                a1.x = fmaf(rh, wB.x, a1.x); a1.y = fmaf(rh, wB.y, a1.y);
                a1.z = fmaf(rh, wB.z, a1.z); a1.w = fmaf(rh, wB.w, a1.w);
            }
            float4 c0 = w3v[kb >> 2], c1 = w3v[(kb >> 2) + 1];
            float partial =
                fmaxf(a0.x,0.f)*c0.x + fmaxf(a0.y,0.f)*c0.y + fmaxf(a0.z,0.f)*c0.z + fmaxf(a0.w,0.f)*c0.w +
                fmaxf(a1.x,0.f)*c1.x + fmaxf(a1.y,0.f)*c1.y + fmaxf(a1.z,0.f)*c1.z + fmaxf(a1.w,0.f)*c1.w;
            sm[SM_PART + s*8 + (tid >> 5)] = partial;
        }
        __syncthreads();
        if (tid < 32) {
            float mech = sm[SM_BM3];
            #pragma unroll
            for (int c = 0; c < 8; ++c) mech += sm[SM_PART + tid*8 + c];
            float pred = (sm[SM_HP] != 0.f) ? mech : sm[SM_X + tid*17 + v];
            out[256 + (gs0 + sub*32 + tid)*16 + v] = pred;
        }
    }
}

// ---------------------------------------------------------------- launch
extern "C" void kernel_launch(void* const* d_in, const int* in_sizes, int n_in,
                              void* d_out, int out_size, void* d_ws, size_t ws_size,
                              hipStream_t stream)
{
    const float* data = (const float*)d_in[0];
    const float* Ws1  = (const float*)d_in[1];
    const float* bs1  = (const float*)d_in[2];
    const float* Ws2  = (const float*)d_in[3];
    const float* bs2  = (const float*)d_in[4];
    const float* Ws3  = (const float*)d_in[5];
    const float* bs3  = (const float*)d_in[6];
    const float* Wm1  = (const float*)d_in[7];
    const float* bm1  = (const float*)d_in[8];
    const float* Wm2  = (const float*)d_in[9];
    const float* bm2  = (const float*)d_in[10];
    const float* Wm3  = (const float*)d_in[11];
    const float* bm3  = (const float*)d_in[12];
    const float* Wt1  = (const float*)d_in[13];
    const float* bt1  = (const float*)d_in[14];
    const float* Wt2  = (const float*)d_in[15];
    const float* bt2  = (const float*)d_in[16];
    float* wsf = (float*)d_ws;
    float* out = (float*)d_out;

    hipLaunchKernelGGL(k_avg, dim3(32), dim3(256), 0, stream,
                       data, Ws1, Ws2, Ws3, wsf);
    hipLaunchKernelGGL(k_graph_pairs, dim3(241), dim3(512), 0, stream,
                       data, Ws1, bs1, Ws2, bs2, Ws3, bs3,
                       Wt1, bt1, Wt2, bt2, wsf, out);
    hipLaunchKernelGGL(k_mech_scores, dim3(513), dim3(256), 0, stream,
                       data, Wm1, bm1, Wm2, bm2, Wm3, bm3, wsf, out);
}

// Round 3
// 122.513 us; speedup vs baseline: 1.3738x; 1.3738x over previous
//
#include <hip/hip_runtime.h>
#include <hip/hip_bf16.h>

// CausalGraphDiscovery on MI355X. f32 buffers holding bf16-rounded values.
// Mech MLP rewritten on bf16 MFMA (16x16x32), fp32 accumulate.
//
// d_out (f32): [0,256) adj | [256,131328) predictions | [131328,131584) scores
//
// ws (f32):
//   [b*272, b*272+272)  : per-avg-block partial P1[16x16] + msum[16]
//   8704..8944  : scores  | 8960..9200 : parent_mask | 9200..9216 : has_parents
//   9400        : dummy   | 16384..147456 : dataT[16][8192]

typedef __attribute__((ext_vector_type(8))) short bf16x8;
typedef __attribute__((ext_vector_type(4))) short bf16x4;
typedef __attribute__((ext_vector_type(4))) float f32x4;

#define DEV __device__ __forceinline__
DEV short f2bf(float f){ __hip_bfloat16 h = __float2bfloat16(f); short s; __builtin_memcpy(&s,&h,2); return s; }
DEV float bf2f(short s){ __hip_bfloat16 h; __builtin_memcpy(&h,&s,2); return __bfloat162float(h); }

#define WS_P1(b)   ((b)*272)
#define WS_SCORES  8704
#define WS_PM      8960
#define WS_HP      9200
#define WS_DUMMY   9400
#define WS_DT      16384

// ---------------------------------------------------------------- kernel A
// jobs: (1) per-block avg partials for corr; (2) transpose data -> dataT;
//       (3) warm L2 with adjacency-MLP weights.
__global__ void __launch_bounds__(256) k_avg(
    const float* __restrict__ data,
    const float* __restrict__ Ws1,
    const float* __restrict__ Ws2,
    const float* __restrict__ Ws3,
    float* __restrict__ wsf, int useDT)
{
    __shared__ float av[16*17];
    int b = blockIdx.x, tid = threadIdx.x;
    int sl = tid >> 4, vv = tid & 15;
    int s = b*16 + sl;
    float acc = 0.f;
    #pragma unroll
    for (int bt = 0; bt < 16; ++bt) acc += data[bt*8192 + s*16 + vv];
    av[sl*17 + vv] = acc * (1.f/16.f);
    __syncthreads();
    int i = tid >> 4, j = tid & 15;
    float p1 = 0.f;
    #pragma unroll
    for (int r = 0; r < 16; ++r) p1 += av[r*17 + i] * av[r*17 + j];
    wsf[WS_P1(b) + tid] = p1;
    if (tid < 16) {
        float ms = 0.f;
        #pragma unroll
        for (int r = 0; r < 16; ++r) ms += av[r*17 + tid];
        wsf[WS_P1(b) + 256 + tid] = ms;
    }
    // job 2: transpose 256 rows -> dataT[v][n] (coalesced stores per v)
    if (useDT) {
        int n = b*256 + tid;
        const float4* dr = (const float4*)(data + n*16);
        float4 r0 = dr[0], r1 = dr[1], r2 = dr[2], r3 = dr[3];
        float row[16] = {r0.x,r0.y,r0.z,r0.w, r1.x,r1.y,r1.z,r1.w,
                         r2.x,r2.y,r2.z,r2.w, r3.x,r3.y,r3.z,r3.w};
        #pragma unroll
        for (int v2 = 0; v2 < 16; ++v2) wsf[WS_DT + v2*8192 + n] = row[v2];
    }
    // job 3: L2 warm for the single graph block's weight reads
    int seg = b >> 3;
    unsigned xr = 0;
    const uint4* w1 = (const uint4*)Ws1;
    for (int e = tid; e < 4096; e += 256) { uint4 u = w1[seg*4096 + e]; xr ^= u.x^u.y^u.z^u.w; }
    const uint4* w2 = (const uint4*)Ws2;
    for (int e = tid; e < 2048; e += 256) { uint4 u = w2[seg*2048 + e]; xr ^= u.x^u.y^u.z^u.w; }
    const uint4* w3 = (const uint4*)Ws3;
    for (int e = tid; e < 2048; e += 256) { uint4 u = w3[seg*2048 + e]; xr ^= u.x^u.y^u.z^u.w; }
    if (xr == 0x9E3779B9u) wsf[WS_DUMMY] = 0.f;
}

// ---------------------------------------------------------------- kernel B
__global__ void __launch_bounds__(512) k_graph_pairs(
    const float* __restrict__ data,
    const float* __restrict__ Ws1, const float* __restrict__ bs1,
    const float* __restrict__ Ws2, const float* __restrict__ bs2,
    const float* __restrict__ Ws3, const float* __restrict__ bs3,
    const float* __restrict__ Wt1, const float* __restrict__ bt1,
    const float* __restrict__ Wt2, const float* __restrict__ bt2,
    float* __restrict__ wsf, float* __restrict__ out, int useDT)
{
    __shared__ float sh[2048];
    int tid = threadIdx.x;

    if (blockIdx.x != 0) {
        int p = blockIdx.x - 1;
        int i = p / 15, jr = p % 15;
        int j = jr + (jr >= i ? 1 : 0);
        float* w0 = sh;        float* w1 = sh + 32;
        float* bb = sh + 64;   float* w2 = sh + 96;
        float* red = sh + 128;
        if (tid < 32) {
            w0[tid] = Wt1[p*64 + tid];
            w1[tid] = Wt1[p*64 + 32 + tid];
            bb[tid] = bt1[p*32 + tid];
            w2[tid] = Wt2[p*32 + tid];
        }
        if (tid == 0) sh[700] = bt2[p];
        __syncthreads();
        float b2s = sh[700];
        const float* dTi = wsf + WS_DT + i*8192;
        const float* dTj = wsf + WS_DT + j*8192;
        float acc = 0.f;
        for (int it = 0; it < 16; ++it) {
            int s = it*512 + tid;
            float xa, xb;
            if (useDT) { xa = dTi[s]; xb = dTj[s]; }
            else       { xa = data[s*16 + i]; xb = data[s*16 + j]; }
            float z = b2s;
            #pragma unroll
            for (int h = 0; h < 32; ++h) {
                float t1 = fmaf(xa, w0[h], fmaf(xb, w1[h], bb[h]));
                z = fmaf(fmaxf(t1, 0.f), w2[h], z);
            }
            acc += 1.f / (1.f + expf(-z));
        }
        red[tid] = acc;
        __syncthreads();
        for (int off = 256; off > 0; off >>= 1) {
            if (tid < off) red[tid] += red[tid + off];
            __syncthreads();
        }
        if (tid == 0) wsf[WS_SCORES + p] = red[0] * (1.f/8192.f);
        return;
    }

    // ---- graph block ----
    float* corr_s = sh;          float* part   = sh + 256;
    float* h1_s   = sh + 768;    float* h2_s   = sh + 1024;
    float* adj_s  = sh + 1152;   float* pm_s   = sh + 1408;
    float* m_s    = sh + 1648;   float* std_s  = sh + 1664;
    float* cov_s  = sh + 1680;

    float p1 = 0.f;
    if (tid < 256) { for (int b = 0; b < 32; ++b) p1 += wsf[WS_P1(b) + tid]; }
    if (tid < 16) {
        float ms = 0.f;
        for (int b = 0; b < 32; ++b) ms += wsf[WS_P1(b) + 256 + tid];
        m_s[tid] = ms * (1.f/512.f);
    }
    __syncthreads();
    if (tid < 256) { int i = tid>>4, j = tid&15; cov_s[tid] = p1 - 512.f*m_s[i]*m_s[j]; }
    __syncthreads();
    if (tid < 16) std_s[tid] = sqrtf(fmaxf(cov_s[tid*17], 0.f));
    __syncthreads();
    if (tid < 256) {
        int i = tid>>4, j = tid&15;
        float den = std_s[i]*std_s[j];
        corr_s[tid] = (den > 0.f && i != j) ? fabsf(cov_s[tid]/den) : 0.f;
    }
    __syncthreads();
    {
        int t = tid & 255, half = tid >> 8;
        float a = 0.f;
        #pragma unroll 8
        for (int i = half*128; i < half*128 + 128; ++i)
            a = fmaf(corr_s[i], Ws1[i*256 + t], a);
        part[half*256 + t] = a;
    }
    __syncthreads();
    if (tid < 256) h1_s[tid] = fmaxf(part[tid] + part[256 + tid] + bs1[tid], 0.f);
    __syncthreads();
    {
        int t = tid & 127, qq = tid >> 7;
        float a = 0.f;
        #pragma unroll 8
        for (int i = qq*64; i < qq*64 + 64; ++i)
            a = fmaf(h1_s[i], Ws2[i*128 + t], a);
        part[qq*128 + t] = a;
    }
    __syncthreads();
    if (tid < 128)
        h2_s[tid] = fmaxf(part[tid] + part[128+tid] + part[256+tid] + part[384+tid] + bs2[tid], 0.f);
    __syncthreads();
    {
        int t = tid & 255, half = tid >> 8;
        float a = 0.f;
        #pragma unroll 8
        for (int i = half*64; i < half*64 + 64; ++i)
            a = fmaf(h2_s[i], Ws3[i*256 + t], a);
        part[half*256 + t] = a;
    }
    __syncthreads();
    if (tid < 256) {
        float z = part[tid] + part[256 + tid] + bs3[tid];
        float a = 1.f / (1.f + expf(-z));
        int r = tid >> 4, cc = tid & 15;
        float adjv = (r < cc) ? a : 0.f;
        adj_s[tid] = adjv;
        out[tid] = adjv;
    }
    __syncthreads();
    if (tid < 240) {
        int v = tid / 15, pr = tid % 15;
        int jj = pr + (pr >= v ? 1 : 0);
        float pmv = (adj_s[jj*16 + v] > 0.5f) ? 1.f : 0.f;
        wsf[WS_PM + tid] = pmv;
        pm_s[tid] = pmv;
    }
    __syncthreads();
    if (tid < 16) {
        float sum = 0.f;
        #pragma unroll
        for (int pr = 0; pr < 15; ++pr) sum += pm_s[tid*15 + pr];
        wsf[WS_HP + tid] = (sum > 0.f) ? 1.f : 0.f;
    }
}

// ---------------------------------------------------------------- kernel C
// bid<512: (v=bid>>5, 256-sample chunk) mech MLP on bf16 MFMA.
//   layer1: D'[h][s] = Wfull^T . X^T  (K=16 padded to 32; mask+self folded
//           into Wfull rows) -> C/D layout has 4 contiguous h per lane ->
//           packed b64 relu/bf16 store into per-wave H1[s][h] (stride 136).
//   layer2: A=H1 (b128 reads), B=Wm2T frags resident in VGPRs.
//   layer3: per-lane dot + shfl_xor(width 16) reduce.
// bid==512: scores scatter.
__global__ void __launch_bounds__(256, 2) k_mech(
    const float* __restrict__ data,
    const float* __restrict__ Wm1, const float* __restrict__ bm1,
    const float* __restrict__ Wm2, const float* __restrict__ bm2,
    const float* __restrict__ Wm3, const float* __restrict__ bm3,
    const float* __restrict__ wsf, float* __restrict__ out)
{
    int tid = threadIdx.x, bid = blockIdx.x;
    if (bid == 512) {
        int i = tid >> 4, j = tid & 15;
        float s = 0.f;
        if (i != j) s = wsf[WS_SCORES + i*15 + j - (j > i ? 1 : 0)];
        out[256 + 131072 + tid] = s;
        return;
    }
    int v = bid >> 5, chunk = bid & 31;
    int gs0 = chunk * 256;

    __shared__ __align__(16) short smX[256*24];     // X bf16, row stride 24
    __shared__ __align__(16) short smW2T[64*136];   // Wm2T[j][h] bf16
    __shared__ __align__(16) short smH1[4][16*136]; // per-wave H1[s][h] bf16
    __shared__ __align__(16) float smW1[16*128];    // Wfull[k][h] fp32
    __shared__ __align__(16) float smB1[128];
    __shared__ float smB2[64];
    __shared__ float smW3[64];

    // ---- stage ----
    for (int e = tid; e < 2048; e += 256) {          // Wfull (mask + self-zero folded)
        int k = e >> 7, h = e & 127;
        float val = 0.f;
        if (k != v) {
            int p = k - (k > v ? 1 : 0);
            val = Wm1[v*1920 + p*128 + h] * wsf[WS_PM + v*15 + p];
        }
        smW1[e] = val;
    }
    for (int e = tid; e < 8192; e += 256) {          // Wm2 transposed -> bf16
        int h = e >> 6, j = e & 63;
        smW2T[j*136 + h] = f2bf(Wm2[v*8192 + e]);
    }
    for (int e = tid; e < 4096; e += 256) {          // X -> bf16 (lossless)
        int s = e >> 4, k = e & 15;
        smX[s*24 + k] = f2bf(data[gs0*16 + e]);
    }
    if (tid < 128) smB1[tid] = bm1[v*128 + tid];
    else if (tid < 192) smB2[tid - 128] = bm2[v*64 + tid - 128];
    else smW3[tid - 192] = Wm3[v*64 + tid - 192];
    __syncthreads();

    int lane = tid & 63, wid = tid >> 6;
    int c = lane & 15, q = lane >> 4;
    float hp = wsf[WS_HP + v];
    float bm3v = bm3[v];

    // A1 frags (Wfull^T): lane elem jj = Wfull[k=q*8+jj][h=ht*16+c]; 0 for k>=16
    bf16x8 a1[8];
    #pragma unroll
    for (int ht = 0; ht < 8; ++ht) {
        #pragma unroll
        for (int jj = 0; jj < 8; ++jj) {
            int k = q*8 + jj;
            float w = (k < 16) ? smW1[k*128 + ht*16 + c] : 0.f;
            a1[ht][jj] = f2bf(w);
        }
    }
    // B2 frags resident: elem jj = Wm2[h=ks*32+q*8+jj][j=jt*16+c]
    bf16x8 b2r[16];
    #pragma unroll
    for (int jt = 0; jt < 4; ++jt)
        #pragma unroll
        for (int ks = 0; ks < 4; ++ks)
            b2r[jt*4 + ks] = *(const bf16x8*)&smW2T[(jt*16 + c)*136 + ks*32 + q*8];
    float w3c[4], b2c[4];
    #pragma unroll
    for (int jt = 0; jt < 4; ++jt) { w3c[jt] = smW3[jt*16 + c]; b2c[jt] = smB2[jt*16 + c]; }

    short* h1buf = smH1[wid];

    for (int stl = 0; stl < 4; ++stl) {
        int st = wid*4 + stl;                        // sample tile: rows st*16..+15
        // ---- layer 1 ----
        bf16x8 xb;
        #pragma unroll
        for (int i2 = 0; i2 < 8; ++i2) xb[i2] = 0;
        if (q < 2) xb = *(const bf16x8*)&smX[(st*16 + c)*24 + q*8];
        f32x4 c1[8];
        #pragma unroll
        for (int ht = 0; ht < 8; ++ht) c1[ht] = *(const f32x4*)&smB1[ht*16 + q*4];
        #pragma unroll
        for (int ht = 0; ht < 8; ++ht)
            c1[ht] = __builtin_amdgcn_mfma_f32_16x16x32_bf16(a1[ht], xb, c1[ht], 0, 0, 0);
        #pragma unroll
        for (int ht = 0; ht < 8; ++ht) {
            bf16x4 pk;
            #pragma unroll
            for (int r = 0; r < 4; ++r) pk[r] = f2bf(fmaxf(c1[ht][r], 0.f));
            *(bf16x4*)&h1buf[c*136 + ht*16 + q*4] = pk;   // H1[s=c][h], same-wave
        }
        // ---- layer 2 ----
        f32x4 c2[4];
        #pragma unroll
        for (int jt = 0; jt < 4; ++jt) {
            float bi = b2c[jt];
            c2[jt] = (f32x4){bi, bi, bi, bi};
        }
        #pragma unroll
        for (int ks = 0; ks < 4; ++ks) {
            bf16x8 a2 = *(const bf16x8*)&h1buf[c*136 + ks*32 + q*8];
            #pragma unroll
            for (int jt = 0; jt < 4; ++jt)
                c2[jt] = __builtin_amdgcn_mfma_f32_16x16x32_bf16(a2, b2r[jt*4 + ks], c2[jt], 0, 0, 0);
        }
        // ---- layer 3: mech[s] = sum_j relu(H2[s][j])*Wm3[j] + bm3 ----
        float part[4];
        #pragma unroll
        for (int r = 0; r < 4; ++r) part[r] = 0.f;
        #pragma unroll
        for (int jt = 0; jt < 4; ++jt)
            #pragma unroll
            for (int r = 0; r < 4; ++r)
                part[r] = fmaf(fmaxf(c2[jt][r], 0.f), w3c[jt], part[r]);
        #pragma unroll
        for (int off = 1; off < 16; off <<= 1)
            #pragma unroll
            for (int r = 0; r < 4; ++r)
                part[r] += __shfl_xor(part[r], off, 16);
        if (c == 0) {
            #pragma unroll
            for (int r = 0; r < 4; ++r) {
                int s_loc = st*16 + q*4 + r;
                float mech = part[r] + bm3v;
                float xv = bf2f(smX[s_loc*24 + v]);
                out[256 + (gs0 + s_loc)*16 + v] = (hp != 0.f) ? mech : xv;
            }
        }
    }
}

// ---------------------------------------------------------------- launch
extern "C" void kernel_launch(void* const* d_in, const int* in_sizes, int n_in,
                              void* d_out, int out_size, void* d_ws, size_t ws_size,
                              hipStream_t stream)
{
    const float* data = (const float*)d_in[0];
    const float* Ws1  = (const float*)d_in[1];
    const float* bs1  = (const float*)d_in[2];
    const float* Ws2  = (const float*)d_in[3];
    const float* bs2  = (const float*)d_in[4];
    const float* Ws3  = (const float*)d_in[5];
    const float* bs3  = (const float*)d_in[6];
    const float* Wm1  = (const float*)d_in[7];
    const float* bm1  = (const float*)d_in[8];
    const float* Wm2  = (const float*)d_in[9];
    const float* bm2  = (const float*)d_in[10];
    const float* Wm3  = (const float*)d_in[11];
    const float* bm3  = (const float*)d_in[12];
    const float* Wt1  = (const float*)d_in[13];
    const float* bt1  = (const float*)d_in[14];
    const float* Wt2  = (const float*)d_in[15];
    const float* bt2  = (const float*)d_in[16];
    float* wsf = (float*)d_ws;
    float* out = (float*)d_out;
    int useDT = (ws_size >= (size_t)(WS_DT + 16*8192) * 4) ? 1 : 0;

    hipLaunchKernelGGL(k_avg, dim3(32), dim3(256), 0, stream,
                       data, Ws1, Ws2, Ws3, wsf, useDT);
    hipLaunchKernelGGL(k_graph_pairs, dim3(241), dim3(512), 0, stream,
                       data, Ws1, bs1, Ws2, bs2, Ws3, bs3,
                       Wt1, bt1, Wt2, bt2, wsf, out, useDT);
    hipLaunchKernelGGL(k_mech, dim3(513), dim3(256), 0, stream,
                       data, Wm1, bm1, Wm2, bm2, Wm3, bm3, wsf, out);
}

// Round 4
// 119.462 us; speedup vs baseline: 1.4089x; 1.0255x over previous
//
#include <hip/hip_runtime.h>
#include <hip/hip_bf16.h>

// CausalGraphDiscovery on MI355X. f32 buffers holding bf16-rounded values.
// Round 4: 2 dispatches. k_main fuses avg-partials + graph chain + pair MLP
// (intra-kernel producer->consumer via agent-scope flags); k_mech does the
// MFMA mech MLP + scores scatter.
//
// d_out (f32): [0,256) adj | [256,131328) predictions | [131328,131584) scores
//
// ws (f32):
//   [b*272, b*272+272) b<32 : avg-partials P1[16x16]+msum[16] (blocks 1..32)
//   8704..8944 : scores | 8960..9200 : parent_mask | 9200..9216 : has_parents
//   9400 : dummy | 9600..9632 (as int) : producer flags

typedef __attribute__((ext_vector_type(8))) short bf16x8;
typedef __attribute__((ext_vector_type(4))) short bf16x4;
typedef __attribute__((ext_vector_type(4))) float f32x4;

#define DEV __device__ __forceinline__
DEV short f2bf(float f){ __hip_bfloat16 h = __float2bfloat16(f); short s; __builtin_memcpy(&s,&h,2); return s; }
DEV float bf2f(short s){ __hip_bfloat16 h; __builtin_memcpy(&h,&s,2); return __bfloat162float(h); }

#define WS_P1(b)   ((b)*272)
#define WS_SCORES  8704
#define WS_PM      8960
#define WS_HP      9200
#define WS_DUMMY   9400
#define WS_FLAG    9600
#define FLAG_MAGIC 0x1357F00D

// ---------------------------------------------------------------- kernel 1
// block 0       : graph chain (waits on flags from blocks 1..32)
// blocks 1..32  : avg partials + weight warm (L3 fill) + flag, then pair MLP
// blocks 33..240: pair MLP
__global__ void __launch_bounds__(512) k_main(
    const float* __restrict__ data,
    const float* __restrict__ Ws1, const float* __restrict__ bs1,
    const float* __restrict__ Ws2, const float* __restrict__ bs2,
    const float* __restrict__ Ws3, const float* __restrict__ bs3,
    const float* __restrict__ Wt1, const float* __restrict__ bt1,
    const float* __restrict__ Wt2, const float* __restrict__ bt2,
    float* __restrict__ wsf, float* __restrict__ out)
{
    __shared__ float sh[2048];
    __shared__ float av[16*17];
    int tid = threadIdx.x;
    int* flags = (int*)(wsf + WS_FLAG);

    if (blockIdx.x != 0) {
        int p = blockIdx.x - 1;      // pair index 0..239

        if (blockIdx.x <= 32) {
            // ---- producer job: avg partials over samples b*16..b*16+15 ----
            int b = blockIdx.x - 1;
            if (tid < 256) {
                int sl = tid >> 4, vv = tid & 15;
                int s = b*16 + sl;
                float acc = 0.f;
                #pragma unroll
                for (int bt = 0; bt < 16; ++bt) acc += data[bt*8192 + s*16 + vv];
                av[sl*17 + vv] = acc * (1.f/16.f);
            }
            __syncthreads();
            if (tid < 256) {
                int i = tid >> 4, j = tid & 15;
                float p1 = 0.f;
                #pragma unroll
                for (int r = 0; r < 16; ++r) p1 += av[r*17 + i] * av[r*17 + j];
                wsf[WS_P1(b) + tid] = p1;
            }
            if (tid < 16) {
                float ms = 0.f;
                #pragma unroll
                for (int r = 0; r < 16; ++r) ms += av[r*17 + tid];
                wsf[WS_P1(b) + 256 + tid] = ms;
            }
            // weight warm (fills shared L3 so block 0's MLP reads miss cheap):
            // 32 blocks x disjoint 16 KB = full 512 KB of Ws1/Ws2/Ws3
            unsigned xr = 0;
            { uint4 u = ((const uint4*)Ws1)[b*512 + tid]; xr ^= u.x^u.y^u.z^u.w; }
            if (tid < 256) { uint4 u = ((const uint4*)Ws2)[b*256 + tid];       xr ^= u.x^u.y^u.z^u.w; }
            else           { uint4 u = ((const uint4*)Ws3)[b*256 + tid - 256]; xr ^= u.x^u.y^u.z^u.w; }
            if (xr == 0x9E3779B9u) wsf[WS_DUMMY] = 0.f;   // defeat DCE
            __syncthreads();
            if (tid == 0) {
                __threadfence();
                __hip_atomic_store(&flags[b], FLAG_MAGIC,
                                   __ATOMIC_RELEASE, __HIP_MEMORY_SCOPE_AGENT);
            }
        }

        // ---- pair MLP for pair p ----
        int i = p / 15, jr = p % 15;
        int j = jr + (jr >= i ? 1 : 0);
        float* w0 = sh;        float* w1 = sh + 32;
        float* bb = sh + 64;   float* w2 = sh + 96;
        float* red = sh + 128;
        if (tid < 32) {
            w0[tid] = Wt1[p*64 + tid];
            w1[tid] = Wt1[p*64 + 32 + tid];
            bb[tid] = bt1[p*32 + tid];
            w2[tid] = Wt2[p*32 + tid];
        }
        if (tid == 0) sh[700] = bt2[p];
        __syncthreads();
        float b2s = sh[700];
        float acc = 0.f;
        for (int it = 0; it < 16; ++it) {
            int s = it*512 + tid;
            float xa = data[s*16 + i];    // row = one 64B line; xb hits L1
            float xb = data[s*16 + j];
            float z = b2s;
            #pragma unroll
            for (int h = 0; h < 32; ++h) {
                float t1 = fmaf(xa, w0[h], fmaf(xb, w1[h], bb[h]));
                z = fmaf(fmaxf(t1, 0.f), w2[h], z);
            }
            acc += 1.f / (1.f + expf(-z));
        }
        red[tid] = acc;
        __syncthreads();
        for (int off = 256; off > 0; off >>= 1) {
            if (tid < off) red[tid] += red[tid + off];
            __syncthreads();
        }
        if (tid == 0) wsf[WS_SCORES + p] = red[0] * (1.f/8192.f);
        return;
    }

    // ---- graph block (block 0) ----
    if (tid < 32) {
        while (__hip_atomic_load(&flags[tid], __ATOMIC_ACQUIRE,
                                 __HIP_MEMORY_SCOPE_AGENT) != FLAG_MAGIC)
            __builtin_amdgcn_s_sleep(2);
    }
    __syncthreads();
    __threadfence();

    float* corr_s = sh;          float* part   = sh + 256;
    float* h1_s   = sh + 768;    float* h2_s   = sh + 1024;
    float* adj_s  = sh + 1152;   float* pm_s   = sh + 1408;
    float* m_s    = sh + 1648;   float* std_s  = sh + 1664;
    float* cov_s  = sh + 1680;

    float p1 = 0.f;
    if (tid < 256) { for (int b = 0; b < 32; ++b) p1 += wsf[WS_P1(b) + tid]; }
    if (tid < 16) {
        float ms = 0.f;
        for (int b = 0; b < 32; ++b) ms += wsf[WS_P1(b) + 256 + tid];
        m_s[tid] = ms * (1.f/512.f);
    }
    __syncthreads();
    if (tid < 256) { int i = tid>>4, j = tid&15; cov_s[tid] = p1 - 512.f*m_s[i]*m_s[j]; }
    __syncthreads();
    if (tid < 16) std_s[tid] = sqrtf(fmaxf(cov_s[tid*17], 0.f));
    __syncthreads();
    if (tid < 256) {
        int i = tid>>4, j = tid&15;
        float den = std_s[i]*std_s[j];
        corr_s[tid] = (den > 0.f && i != j) ? fabsf(cov_s[tid]/den) : 0.f;
    }
    __syncthreads();
    {   // layer1: 256 outputs, K split in 2
        int t = tid & 255, half = tid >> 8;
        float a = 0.f;
        #pragma unroll 8
        for (int i = half*128; i < half*128 + 128; ++i)
            a = fmaf(corr_s[i], Ws1[i*256 + t], a);
        part[half*256 + t] = a;
    }
    __syncthreads();
    if (tid < 256) h1_s[tid] = fmaxf(part[tid] + part[256 + tid] + bs1[tid], 0.f);
    __syncthreads();
    {   // layer2: 128 outputs, K split in 4
        int t = tid & 127, qq = tid >> 7;
        float a = 0.f;
        #pragma unroll 8
        for (int i = qq*64; i < qq*64 + 64; ++i)
            a = fmaf(h1_s[i], Ws2[i*128 + t], a);
        part[qq*128 + t] = a;
    }
    __syncthreads();
    if (tid < 128)
        h2_s[tid] = fmaxf(part[tid] + part[128+tid] + part[256+tid] + part[384+tid] + bs2[tid], 0.f);
    __syncthreads();
    {   // layer3: 256 outputs, K split in 2
        int t = tid & 255, half = tid >> 8;
        float a = 0.f;
        #pragma unroll 8
        for (int i = half*64; i < half*64 + 64; ++i)
            a = fmaf(h2_s[i], Ws3[i*256 + t], a);
        part[half*256 + t] = a;
    }
    __syncthreads();
    if (tid < 256) {
        float z = part[tid] + part[256 + tid] + bs3[tid];
        float a = 1.f / (1.f + expf(-z));
        int r = tid >> 4, cc = tid & 15;
        float adjv = (r < cc) ? a : 0.f;     // triu(adj,1)
        adj_s[tid] = adjv;
        out[tid] = adjv;
    }
    __syncthreads();
    if (tid < 240) {
        int v = tid / 15, pr = tid % 15;
        int jj = pr + (pr >= v ? 1 : 0);
        float pmv = (adj_s[jj*16 + v] > 0.5f) ? 1.f : 0.f;
        wsf[WS_PM + tid] = pmv;
        pm_s[tid] = pmv;
    }
    __syncthreads();
    if (tid < 16) {
        float sum = 0.f;
        #pragma unroll
        for (int pr = 0; pr < 15; ++pr) sum += pm_s[tid*15 + pr];
        wsf[WS_HP + tid] = (sum > 0.f) ? 1.f : 0.f;
    }
}

// ---------------------------------------------------------------- kernel 2
// 512 blocks: (v=bid>>5, 256-sample chunk) mech MLP on bf16 MFMA.
// block 0 additionally scatters scores at the end.
__global__ void __launch_bounds__(256, 2) k_mech(
    const float* __restrict__ data,
    const float* __restrict__ Wm1, const float* __restrict__ bm1,
    const float* __restrict__ Wm2, const float* __restrict__ bm2,
    const float* __restrict__ Wm3, const float* __restrict__ bm3,
    const float* __restrict__ wsf, float* __restrict__ out)
{
    int tid = threadIdx.x, bid = blockIdx.x;
    int v = bid >> 5, chunk = bid & 31;
    int gs0 = chunk * 256;

    __shared__ __align__(16) short smX[256*24];
    __shared__ __align__(16) short smW2T[64*136];
    __shared__ __align__(16) short smH1[4][16*136];
    __shared__ __align__(16) float smW1[16*128];
    __shared__ __align__(16) float smB1[128];
    __shared__ float smB2[64];
    __shared__ float smW3[64];

    for (int e = tid; e < 2048; e += 256) {          // Wfull (mask+self folded)
        int k = e >> 7, h = e & 127;
        float val = 0.f;
        if (k != v) {
            int p = k - (k > v ? 1 : 0);
            val = Wm1[v*1920 + p*128 + h] * wsf[WS_PM + v*15 + p];
        }
        smW1[e] = val;
    }
    for (int e = tid; e < 8192; e += 256) {          // Wm2^T -> bf16
        int h = e >> 6, j = e & 63;
        smW2T[j*136 + h] = f2bf(Wm2[v*8192 + e]);
    }
    for (int e = tid; e < 4096; e += 256) {          // X -> bf16 (lossless)
        int s = e >> 4, k = e & 15;
        smX[s*24 + k] = f2bf(data[gs0*16 + e]);
    }
    if (tid < 128) smB1[tid] = bm1[v*128 + tid];
    else if (tid < 192) smB2[tid - 128] = bm2[v*64 + tid - 128];
    else smW3[tid - 192] = Wm3[v*64 + tid - 192];
    __syncthreads();

    int lane = tid & 63, wid = tid >> 6;
    int c = lane & 15, q = lane >> 4;
    float hp = wsf[WS_HP + v];
    float bm3v = bm3[v];

    bf16x8 a1[8];
    #pragma unroll
    for (int ht = 0; ht < 8; ++ht) {
        #pragma unroll
        for (int jj = 0; jj < 8; ++jj) {
            int k = q*8 + jj;
            float w = (k < 16) ? smW1[k*128 + ht*16 + c] : 0.f;
            a1[ht][jj] = f2bf(w);
        }
    }
    bf16x8 b2r[16];
    #pragma unroll
    for (int jt = 0; jt < 4; ++jt)
        #pragma unroll
        for (int ks = 0; ks < 4; ++ks)
            b2r[jt*4 + ks] = *(const bf16x8*)&smW2T[(jt*16 + c)*136 + ks*32 + q*8];
    float w3c[4], b2c[4];
    #pragma unroll
    for (int jt = 0; jt < 4; ++jt) { w3c[jt] = smW3[jt*16 + c]; b2c[jt] = smB2[jt*16 + c]; }

    short* h1buf = smH1[wid];

    for (int stl = 0; stl < 4; ++stl) {
        int st = wid*4 + stl;
        bf16x8 xb;
        #pragma unroll
        for (int i2 = 0; i2 < 8; ++i2) xb[i2] = 0;
        if (q < 2) xb = *(const bf16x8*)&smX[(st*16 + c)*24 + q*8];
        f32x4 c1[8];
        #pragma unroll
        for (int ht = 0; ht < 8; ++ht) c1[ht] = *(const f32x4*)&smB1[ht*16 + q*4];
        #pragma unroll
        for (int ht = 0; ht < 8; ++ht)
            c1[ht] = __builtin_amdgcn_mfma_f32_16x16x32_bf16(a1[ht], xb, c1[ht], 0, 0, 0);
        #pragma unroll
        for (int ht = 0; ht < 8; ++ht) {
            bf16x4 pk;
            #pragma unroll
            for (int r = 0; r < 4; ++r) pk[r] = f2bf(fmaxf(c1[ht][r], 0.f));
            *(bf16x4*)&h1buf[c*136 + ht*16 + q*4] = pk;
        }
        f32x4 c2[4];
        #pragma unroll
        for (int jt = 0; jt < 4; ++jt) {
            float bi = b2c[jt];
            c2[jt] = (f32x4){bi, bi, bi, bi};
        }
        #pragma unroll
        for (int ks = 0; ks < 4; ++ks) {
            bf16x8 a2 = *(const bf16x8*)&h1buf[c*136 + ks*32 + q*8];
            #pragma unroll
            for (int jt = 0; jt < 4; ++jt)
                c2[jt] = __builtin_amdgcn_mfma_f32_16x16x32_bf16(a2, b2r[jt*4 + ks], c2[jt], 0, 0, 0);
        }
        float part[4];
        #pragma unroll
        for (int r = 0; r < 4; ++r) part[r] = 0.f;
        #pragma unroll
        for (int jt = 0; jt < 4; ++jt)
            #pragma unroll
            for (int r = 0; r < 4; ++r)
                part[r] = fmaf(fmaxf(c2[jt][r], 0.f), w3c[jt], part[r]);
        #pragma unroll
        for (int off = 1; off < 16; off <<= 1)
            #pragma unroll
            for (int r = 0; r < 4; ++r)
                part[r] += __shfl_xor(part[r], off, 16);
        if (c == 0) {
            #pragma unroll
            for (int r = 0; r < 4; ++r) {
                int s_loc = st*16 + q*4 + r;
                float mech = part[r] + bm3v;
                float xv = bf2f(smX[s_loc*24 + v]);
                out[256 + (gs0 + s_loc)*16 + v] = (hp != 0.f) ? mech : xv;
            }
        }
    }

    if (bid == 0 && tid < 256) {   // scores scatter
        int i = tid >> 4, j = tid & 15;
        float s = 0.f;
        if (i != j) s = wsf[WS_SCORES + i*15 + j - (j > i ? 1 : 0)];
        out[256 + 131072 + tid] = s;
    }
}

// ---------------------------------------------------------------- launch
extern "C" void kernel_launch(void* const* d_in, const int* in_sizes, int n_in,
                              void* d_out, int out_size, void* d_ws, size_t ws_size,
                              hipStream_t stream)
{
    const float* data = (const float*)d_in[0];
    const float* Ws1  = (const float*)d_in[1];
    const float* bs1  = (const float*)d_in[2];
    const float* Ws2  = (const float*)d_in[3];
    const float* bs2  = (const float*)d_in[4];
    const float* Ws3  = (const float*)d_in[5];
    const float* bs3  = (const float*)d_in[6];
    const float* Wm1  = (const float*)d_in[7];
    const float* bm1  = (const float*)d_in[8];
    const float* Wm2  = (const float*)d_in[9];
    const float* bm2  = (const float*)d_in[10];
    const float* Wm3  = (const float*)d_in[11];
    const float* bm3  = (const float*)d_in[12];
    const float* Wt1  = (const float*)d_in[13];
    const float* bt1  = (const float*)d_in[14];
    const float* Wt2  = (const float*)d_in[15];
    const float* bt2  = (const float*)d_in[16];
    float* wsf = (float*)d_ws;
    float* out = (float*)d_out;

    hipLaunchKernelGGL(k_main, dim3(241), dim3(512), 0, stream,
                       data, Ws1, bs1, Ws2, bs2, Ws3, bs3,
                       Wt1, bt1, Wt2, bt2, wsf, out);
    hipLaunchKernelGGL(k_mech, dim3(512), dim3(256), 0, stream,
                       data, Wm1, bm1, Wm2, bm2, Wm3, bm3, wsf, out);
}